// Round 8
// baseline (835.487 us; speedup 1.0000x reference)
//
#include <hip/hip_runtime.h>

// Depthwise 7x7 VALID conv, fp32, NCHW.
// x: (16,256,128,128), w: (256,7,7), out: (16,256,122,122)
// 8-wave-tier version: RB=2 x CB=4 micro-tile keeps live state ~40 floats so
// __launch_bounds__(256,8) fits the <=64-VGPR tier (8 waves/SIMD) without
// scratch demotion. No LDS. Zero load clamps / store masks by geometry:
// x0 in {0,58}, y0 in {0,32,64,90}; overlap tiles write identical values.
// Weights forced to SGPRs via readfirstlane. float2 loads (8B-aligned).

#define BATCH 16
#define CHAN  256
#define H_IN  128
#define W_IN  128
#define KS    7
#define H_OUT 122
#define W_OUT 122

#define RB 2           // output rows per thread
#define CB 4           // output cols per thread

typedef float v2f __attribute__((ext_vector_type(2)));

__device__ __forceinline__ float sgpr_bcast(float v) {
    return __int_as_float(__builtin_amdgcn_readfirstlane(__float_as_int(v)));
}

__global__ __launch_bounds__(256, 8)
void dwconv7x7_kernel(const float* __restrict__ x,
                      const float* __restrict__ w,
                      float* __restrict__ out) {
    // ---- chunked XCD swizzle: 8 tiles of an image stay on one XCD ----
    const int s   = blockIdx.x;                  // 32768 blocks (%8 == 0)
    const int wid = (s & 7) * 4096 + (s >> 3);   // bijective
    const int img = wid >> 3;                    // b*CHAN + c
    const int t   = wid & 7;                     // tile id 0..7
    const int ch  = img & (CHAN - 1);

    const int x0 = (t & 1) * 58;                 // 0 or 58 (even -> 8B align)
    const int yt = t >> 1;                       // 0..3
    const int y0 = yt * 32 - ((yt == 3) ? 6 : 0);  // 0,32,64,90

    const int tx = threadIdx.x & 15;             // 16 col groups x 4 = 64 cols
    const int ty = threadIdx.x >> 4;             // 16 row groups x 2 = 32 rows

    const int ox = x0 + tx * CB;                 // <= 118, even
    const int oy = y0 + ty * RB;                 // <= 120

    // ---- weights: block-uniform -> force into SGPRs ----
    const float* __restrict__ wp = w + ch * (KS * KS);
    float wr[KS * KS];
    #pragma unroll
    for (int i = 0; i < KS * KS; ++i) wr[i] = sgpr_bcast(wp[i]);

    // input: rows oy..oy+7 (<=127), cols ox..ox+9 (<=127) -- all in bounds
    const float* __restrict__ xp =
        x + (size_t)img * (H_IN * W_IN) + (size_t)oy * W_IN + ox;

    float acc[RB][CB] = {};

    #pragma unroll
    for (int r = 0; r < RB + KS - 1; ++r) {      // 8 input rows
        const float* row = xp + r * W_IN;
        float win[CB + KS - 1];                  // 10 floats (5 x float2)
        #pragma unroll
        for (int j = 0; j < (CB + KS - 1) / 2; ++j) {
            const v2f v = *reinterpret_cast<const v2f*>(row + 2 * j);
            win[2 * j]     = v.x;
            win[2 * j + 1] = v.y;
        }
        #pragma unroll
        for (int i = 0; i < RB; ++i) {
            const int ky = r - i;
            if (ky >= 0 && ky < KS) {
                #pragma unroll
                for (int kx = 0; kx < KS; ++kx) {
                    const float wv = wr[ky * KS + kx];
                    #pragma unroll
                    for (int cc = 0; cc < CB; ++cc)
                        acc[i][cc] = fmaf(win[kx + cc], wv, acc[i][cc]);
                }
            }
        }
    }

    // ---- stores: all in-bounds by construction (cols <=121, rows <=121) ----
    float* __restrict__ op =
        out + (size_t)img * (H_OUT * W_OUT) + (size_t)oy * W_OUT + ox;
    #pragma unroll
    for (int i = 0; i < RB; ++i) {
        float* q = op + i * W_OUT;
        #pragma unroll
        for (int j = 0; j < CB / 2; ++j) {
            v2f v;
            v.x = acc[i][2 * j];
            v.y = acc[i][2 * j + 1];
            __builtin_nontemporal_store(v, reinterpret_cast<v2f*>(q) + j);
        }
    }
}

extern "C" void kernel_launch(void* const* d_in, const int* in_sizes, int n_in,
                              void* d_out, int out_size, void* d_ws, size_t ws_size,
                              hipStream_t stream) {
    const float* x = (const float*)d_in[0];
    const float* w = (const float*)d_in[1];
    float* out = (float*)d_out;

    // 8 blocks per image (2 col-tiles x 4 row-tiles), 4096 images
    dim3 grid(8 * BATCH * CHAN, 1, 1);   // 32768 blocks
    dim3 block(256, 1, 1);
    dwconv7x7_kernel<<<grid, block, 0, stream>>>(x, w, out);
}

// Round 9
// 134.269 us; speedup vs baseline: 6.2225x; 6.2225x over previous
//
#include <hip/hip_runtime.h>

// Depthwise 7x7 VALID conv, fp32, NCHW.
// x: (16,256,128,128), w: (256,7,7), out: (16,256,122,122)
// R7 geometry WITHOUT any waves-per-EU hint (hints proven to trigger
// scratch demotion on this ROCm: R2/R5/R7). RB=2 x CB=4 micro-tile,
// demand ~35 VGPR; hoping the allocator stays at the <=64 cliff for
// 8 waves/SIMD. No LDS. Zero load clamps / store masks by geometry:
// x0 in {0,58}, y0 in {0,32,64,90}; overlapping tiles write identical
// values. Weights forced to SGPRs via readfirstlane. float2 loads.

#define BATCH 16
#define CHAN  256
#define H_IN  128
#define W_IN  128
#define KS    7
#define H_OUT 122
#define W_OUT 122

#define RB 2           // output rows per thread
#define CB 4           // output cols per thread

typedef float v2f __attribute__((ext_vector_type(2)));

__device__ __forceinline__ float sgpr_bcast(float v) {
    return __int_as_float(__builtin_amdgcn_readfirstlane(__float_as_int(v)));
}

__global__ __launch_bounds__(256)
void dwconv7x7_kernel(const float* __restrict__ x,
                      const float* __restrict__ w,
                      float* __restrict__ out) {
    // ---- chunked XCD swizzle: 8 tiles of an image stay on one XCD ----
    const int s   = blockIdx.x;                  // 32768 blocks (%8 == 0)
    const int wid = (s & 7) * 4096 + (s >> 3);   // bijective
    const int img = wid >> 3;                    // b*CHAN + c
    const int t   = wid & 7;                     // tile id 0..7
    const int ch  = img & (CHAN - 1);

    const int x0 = (t & 1) * 58;                 // 0 or 58 (even -> 8B align)
    const int yt = t >> 1;                       // 0..3
    const int y0 = yt * 32 - ((yt == 3) ? 6 : 0);  // 0,32,64,90

    const int tx = threadIdx.x & 15;             // 16 col groups x 4 = 64 cols
    const int ty = threadIdx.x >> 4;             // 16 row groups x 2 = 32 rows

    const int ox = x0 + tx * CB;                 // <= 118, even
    const int oy = y0 + ty * RB;                 // <= 120

    // ---- weights: block-uniform -> force into SGPRs ----
    const float* __restrict__ wp = w + ch * (KS * KS);
    float wr[KS * KS];
    #pragma unroll
    for (int i = 0; i < KS * KS; ++i) wr[i] = sgpr_bcast(wp[i]);

    // input: rows oy..oy+7 (<=127), cols ox..ox+9 (<=127) -- all in bounds
    const float* __restrict__ xp =
        x + (size_t)img * (H_IN * W_IN) + (size_t)oy * W_IN + ox;

    float acc[RB][CB] = {};

    #pragma unroll
    for (int r = 0; r < RB + KS - 1; ++r) {      // 8 input rows
        const float* row = xp + r * W_IN;
        float win[CB + KS - 1];                  // 10 floats (5 x float2)
        #pragma unroll
        for (int j = 0; j < (CB + KS - 1) / 2; ++j) {
            const v2f v = *reinterpret_cast<const v2f*>(row + 2 * j);
            win[2 * j]     = v.x;
            win[2 * j + 1] = v.y;
        }
        #pragma unroll
        for (int i = 0; i < RB; ++i) {
            const int ky = r - i;
            if (ky >= 0 && ky < KS) {
                #pragma unroll
                for (int kx = 0; kx < KS; ++kx) {
                    const float wv = wr[ky * KS + kx];
                    #pragma unroll
                    for (int cc = 0; cc < CB; ++cc)
                        acc[i][cc] = fmaf(win[kx + cc], wv, acc[i][cc]);
                }
            }
        }
    }

    // ---- stores: all in-bounds by construction (cols <=121, rows <=121) ----
    float* __restrict__ op =
        out + (size_t)img * (H_OUT * W_OUT) + (size_t)oy * W_OUT + ox;
    #pragma unroll
    for (int i = 0; i < RB; ++i) {
        float* q = op + i * W_OUT;
        #pragma unroll
        for (int j = 0; j < CB / 2; ++j) {
            v2f v;
            v.x = acc[i][2 * j];
            v.y = acc[i][2 * j + 1];
            __builtin_nontemporal_store(v, reinterpret_cast<v2f*>(q) + j);
        }
    }
}

extern "C" void kernel_launch(void* const* d_in, const int* in_sizes, int n_in,
                              void* d_out, int out_size, void* d_ws, size_t ws_size,
                              hipStream_t stream) {
    const float* x = (const float*)d_in[0];
    const float* w = (const float*)d_in[1];
    float* out = (float*)d_out;

    // 8 blocks per image (2 col-tiles x 4 row-tiles), 4096 images
    dim3 grid(8 * BATCH * CHAN, 1, 1);   // 32768 blocks
    dim3 block(256, 1, 1);
    dwconv7x7_kernel<<<grid, block, 0, stream>>>(x, w, out);
}

// Round 10
// 99.318 us; speedup vs baseline: 8.4122x; 1.3519x over previous
//
#include <hip/hip_runtime.h>

// Depthwise 7x7 VALID conv, fp32, NCHW.
// x: (16,256,128,128), w: (256,7,7), out: (16,256,122,122)
// Column-sweep structure: each thread owns an even column pair (c, c+1) and
// sweeps vertically through 70 input rows, maintaining a 7-slot ring of
// output-row accumulators. Per step: 4 float2 loads (8-float window) feed
// 98 FMAs -> load latency self-hidden by arithmetic. One output row stored
// per steady-state step. No LDS, no bounds checks, no launch-bounds hint
// (hints proven to trigger scratch demotion: R2/R5/R7).
// Wave = one (image, row-half): channel-uniform -> weights in SGPRs.
// lanes 0-31: cols 0..63; lanes 32-63: cols 58..121 (overlap identical).
// row-half 0: inputs 0..69 -> outputs 0..63; row-half 1: inputs 58..127 ->
// outputs 58..121 (overlap rows written with identical values).

#define BATCH 16
#define CHAN  256
#define H_IN  128
#define W_IN  128
#define KS    7
#define H_OUT 122
#define W_OUT 122

typedef float v2f __attribute__((ext_vector_type(2)));

__device__ __forceinline__ float sgpr_bcast(float v) {
    return __int_as_float(__builtin_amdgcn_readfirstlane(__float_as_int(v)));
}

__global__ __launch_bounds__(256)
void dwconv7x7_kernel(const float* __restrict__ x,
                      const float* __restrict__ w,
                      float* __restrict__ out) {
    const int lane = threadIdx.x & 63;
    const int unit = blockIdx.x * 4 + (threadIdx.x >> 6);  // (img, rowhalf)
    const int img  = unit >> 1;                            // b*CHAN + c
    const int rh   = unit & 1;
    const int ch   = img & (CHAN - 1);

    int c = 2 * lane;                 // lanes 0..31 -> cols 0..62
    if (lane >= 32) c -= 6;           // lanes 32..63 -> cols 58..120
    const int r0 = rh ? (H_IN - 70) : 0;   // input row base: 0 or 58

    // ---- weights: wave-uniform channel -> force into SGPRs ----
    const float* __restrict__ wp = w + ch * (KS * KS);
    float wr[KS * KS];
    #pragma unroll
    for (int i = 0; i < KS * KS; ++i) wr[i] = sgpr_bcast(wp[i]);

    // input window cols c..c+7 (max 127), rows r0..r0+69 (max 127): in bounds
    const float* __restrict__ xq =
        x + (size_t)img * (H_IN * W_IN) + (size_t)r0 * W_IN + c;
    float* __restrict__ oq =
        out + (size_t)img * (H_OUT * W_OUT) + (size_t)r0 * W_OUT + c;

    float acc[KS][2] = {};            // ring: slot = output_row % 7
    float f[8];                       // 8-float horizontal window

    #define LOADW() do {                                                   \
        const v2f a0 = *reinterpret_cast<const v2f*>(xq);                  \
        const v2f a1 = *reinterpret_cast<const v2f*>(xq + 2);              \
        const v2f a2 = *reinterpret_cast<const v2f*>(xq + 4);              \
        const v2f a3 = *reinterpret_cast<const v2f*>(xq + 6);              \
        f[0] = a0.x; f[1] = a0.y; f[2] = a1.x; f[3] = a1.y;                \
        f[4] = a2.x; f[5] = a2.y; f[6] = a3.x; f[7] = a3.y; } while (0)

    #define ACCUM(SLOT, KY) do {                                           \
        _Pragma("unroll")                                                  \
        for (int kx = 0; kx < 7; ++kx) {                                   \
            const float wv = wr[(KY) * 7 + kx];                            \
            acc[(SLOT)][0] = fmaf(f[kx],     wv, acc[(SLOT)][0]);          \
            acc[(SLOT)][1] = fmaf(f[kx + 1], wv, acc[(SLOT)][1]);          \
        } } while (0)

    // ---- prologue: s = 0..5, only ky <= s (output rows >= 0) ----
    #pragma unroll
    for (int s = 0; s < 6; ++s) {
        LOADW();
        #pragma unroll
        for (int ky = 0; ky <= s; ++ky)
            ACCUM((s - ky) % KS, ky);
        xq += W_IN;
    }

    // ---- main: s = 6 + 7*sb + u, sb rolled (I-cache), u unrolled ----
    for (int sb = 0; sb < 9; ++sb) {
        #pragma unroll
        for (int u = 0; u < 7; ++u) {
            LOADW();
            #pragma unroll
            for (int ky = 0; ky < KS; ++ky)
                ACCUM((6 + u - ky + 7) % KS, ky);      // slot = (s-ky) % 7
            // output row o = s-6 complete; slot = (s-6)%7 = u
            v2f v; v.x = acc[u][0]; v.y = acc[u][1];
            __builtin_nontemporal_store(v, reinterpret_cast<v2f*>(oq));
            acc[u][0] = 0.f; acc[u][1] = 0.f;
            xq += W_IN; oq += W_OUT;
        }
    }

    // ---- tail: s = 69 (stores slot 0 -> local output row 63) ----
    {
        LOADW();
        #pragma unroll
        for (int ky = 0; ky < KS; ++ky)
            ACCUM((6 - ky + 7) % KS, ky);
        v2f v; v.x = acc[0][0]; v.y = acc[0][1];
        __builtin_nontemporal_store(v, reinterpret_cast<v2f*>(oq));
    }

    #undef LOADW
    #undef ACCUM
}

extern "C" void kernel_launch(void* const* d_in, const int* in_sizes, int n_in,
                              void* d_out, int out_size, void* d_ws, size_t ws_size,
                              hipStream_t stream) {
    const float* x = (const float*)d_in[0];
    const float* w = (const float*)d_in[1];
    float* out = (float*)d_out;

    // units = 4096 images x 2 row-halves = 8192 waves; 4 waves per block
    dim3 grid(8192 / 4, 1, 1);   // 2048 blocks
    dim3 block(256, 1, 1);
    dwconv7x7_kernel<<<grid, block, 0, stream>>>(x, w, out);
}

// Round 11
// 95.439 us; speedup vs baseline: 8.7541x; 1.0406x over previous
//
#include <hip/hip_runtime.h>

// Depthwise 7x7 VALID conv, fp32, NCHW.
// x: (16,256,128,128), w: (256,7,7), out: (16,256,122,122)
// Column-sweep with 7-slot ring accumulator (R9), split into 4 row-quarters
// per image for 2x machine oversubscription (16384 waves). Block = 4 waves =
// one image's 4 quarters: halo rows overlap in same-CU L1, weights
// block-uniform. Per step: 4 float2 loads -> 98 FMAs -> 1 float2 store.
// No LDS, no bounds checks, no launch-bounds min-waves hint (demotion!).
// lanes 0-31: cols 0..63; lanes 32-63: cols 58..121 (overlap identical).
// Quarters: r0 in {0,30,60,90}, 38-row sweep -> 32 output rows each;
// 2-row overlaps written with identical values.

#define BATCH 16
#define CHAN  256
#define H_IN  128
#define W_IN  128
#define KS    7
#define H_OUT 122
#define W_OUT 122

typedef float v2f __attribute__((ext_vector_type(2)));

__device__ __forceinline__ float sgpr_bcast(float v) {
    return __int_as_float(__builtin_amdgcn_readfirstlane(__float_as_int(v)));
}

__global__ __launch_bounds__(256)
void dwconv7x7_kernel(const float* __restrict__ x,
                      const float* __restrict__ w,
                      float* __restrict__ out) {
    const int lane = threadIdx.x & 63;
    const int img  = blockIdx.x;                 // b*CHAN + c (one image/block)
    const int q    = threadIdx.x >> 6;           // row-quarter 0..3
    const int ch   = img & (CHAN - 1);

    int c = 2 * lane;                 // lanes 0..31 -> cols 0..62
    if (lane >= 32) c -= 6;           // lanes 32..63 -> cols 58..120
    const int r0 = 30 * q;            // 0,30,60,90; sweep rows r0..r0+37

    // ---- weights: block-uniform -> force into SGPRs ----
    const float* __restrict__ wp = w + ch * (KS * KS);
    float wr[KS * KS];
    #pragma unroll
    for (int i = 0; i < KS * KS; ++i) wr[i] = sgpr_bcast(wp[i]);

    // input cols c..c+7 (max 127), rows r0..r0+37 (max 127): all in bounds
    const float* __restrict__ xq =
        x + (size_t)img * (H_IN * W_IN) + (size_t)r0 * W_IN + c;
    float* __restrict__ oq =
        out + (size_t)img * (H_OUT * W_OUT) + (size_t)r0 * W_OUT + c;

    float acc[KS][2] = {};            // ring: slot = (local output row) % 7
    float f[8];                       // 8-float horizontal window

    #define LOADW() do {                                                   \
        const v2f a0 = *reinterpret_cast<const v2f*>(xq);                  \
        const v2f a1 = *reinterpret_cast<const v2f*>(xq + 2);              \
        const v2f a2 = *reinterpret_cast<const v2f*>(xq + 4);              \
        const v2f a3 = *reinterpret_cast<const v2f*>(xq + 6);              \
        f[0] = a0.x; f[1] = a0.y; f[2] = a1.x; f[3] = a1.y;                \
        f[4] = a2.x; f[5] = a2.y; f[6] = a3.x; f[7] = a3.y; } while (0)

    #define ACCUM(SLOT, KY) do {                                           \
        _Pragma("unroll")                                                  \
        for (int kx = 0; kx < 7; ++kx) {                                   \
            const float wv = wr[(KY) * 7 + kx];                            \
            acc[(SLOT)][0] = fmaf(f[kx],     wv, acc[(SLOT)][0]);          \
            acc[(SLOT)][1] = fmaf(f[kx + 1], wv, acc[(SLOT)][1]);          \
        } } while (0)

    #define MAINSTEP(U) do {                                               \
        LOADW();                                                           \
        _Pragma("unroll")                                                  \
        for (int ky = 0; ky < KS; ++ky)                                    \
            ACCUM((6 + (U) - ky + 7) % KS, ky);                            \
        v2f v; v.x = acc[(U)][0]; v.y = acc[(U)][1];                       \
        __builtin_nontemporal_store(v, reinterpret_cast<v2f*>(oq));        \
        acc[(U)][0] = 0.f; acc[(U)][1] = 0.f;                              \
        xq += W_IN; oq += W_OUT; } while (0)

    // ---- prologue: s = 0..5, only ky <= s ----
    #pragma unroll
    for (int s = 0; s < 6; ++s) {
        LOADW();
        #pragma unroll
        for (int ky = 0; ky <= s; ++ky)
            ACCUM((s - ky) % KS, ky);
        xq += W_IN;
    }

    // ---- main: 28 steps (s=6..33), slot/store index u = (s-6) % 7 ----
    for (int sb = 0; sb < 4; ++sb) {
        #pragma unroll
        for (int u = 0; u < 7; ++u) {
            MAINSTEP(u);
        }
    }

    // ---- tail: 4 steps (s=34..37, 34%7==6 -> same slot math, u=0..3) ----
    #pragma unroll
    for (int t = 0; t < 4; ++t) {
        MAINSTEP(t);
    }

    #undef LOADW
    #undef ACCUM
    #undef MAINSTEP
}

extern "C" void kernel_launch(void* const* d_in, const int* in_sizes, int n_in,
                              void* d_out, int out_size, void* d_ws, size_t ws_size,
                              hipStream_t stream) {
    const float* x = (const float*)d_in[0];
    const float* w = (const float*)d_in[1];
    float* out = (float*)d_out;

    // one block per image; 4 waves = 4 row-quarters
    dim3 grid(BATCH * CHAN, 1, 1);   // 4096 blocks
    dim3 block(256, 1, 1);
    dwconv7x7_kernel<<<grid, block, 0, stream>>>(x, w, out);
}